// Round 1
// baseline (175.574 us; speedup 1.0000x reference)
//
#include <hip/hip_runtime.h>
#include <stdint.h>

#define BATCH 32
#define HH 64
#define WW 64
#define CINX 128
#define FOUT 256
#define NCLS 10

typedef __bf16 bf16x8 __attribute__((ext_vector_type(8)));
typedef float f32x4 __attribute__((ext_vector_type(4)));

// ---------------------------------------------------------------------------
// Prep: kernel [cls][ky][kx][c][f] f32  ->  wt [cls*9+tap][f][c] bf16
// One block per (cls,tap) slab of 128x256. LDS tile transpose (row stride 260
// bf16 to spread transpose-read banks).
// ---------------------------------------------------------------------------
__global__ __launch_bounds__(256) void prep_weights(const float* __restrict__ kin,
                                                    __bf16* __restrict__ wt) {
    __shared__ __bf16 tile[128 * 260];
    const int slab = blockIdx.x;  // 0..89
    const float* src = kin + (size_t)slab * (CINX * FOUT);
    __bf16* dst = wt + (size_t)slab * (FOUT * CINX);
    const int t = threadIdx.x;

    // load 128x256 f32 coalesced (float4 along f), convert, store [c][f] tile
#pragma unroll
    for (int i = 0; i < 32; ++i) {
        int e4 = t + i * 256;      // float4 index, 0..8191
        int c  = e4 >> 6;
        int f4 = e4 & 63;
        f32x4 v = *(const f32x4*)(src + (size_t)e4 * 4);
        __bf16* p = &tile[c * 260 + f4 * 4];
        p[0] = (__bf16)v[0]; p[1] = (__bf16)v[1];
        p[2] = (__bf16)v[2]; p[3] = (__bf16)v[3];
    }
    __syncthreads();
    // write transposed: unit g = 8 c's at fixed f, coalesced 16B stores
#pragma unroll
    for (int i = 0; i < 16; ++i) {
        int g  = t + i * 256;      // 16B unit, 0..4095
        int f  = g >> 4;
        int c0 = (g & 15) * 8;
        bf16x8 o;
#pragma unroll
        for (int j = 0; j < 8; ++j) o[j] = tile[(c0 + j) * 260 + f];
        *(bf16x8*)(dst + (size_t)g * 8) = o;
    }
}

// ---------------------------------------------------------------------------
// Main: implicit-GEMM conv. Block = 128 pixels (2 rows) x 256 features.
// K loop: 9 taps x 128 cin. 8 waves (2M x 4N), MFMA 16x16x32 bf16.
// LDS A[128px][128c], Bt[256f][128c] bf16, XOR-swizzled 16B units.
// ---------------------------------------------------------------------------
__global__ __launch_bounds__(512, 2) void conv_main(
    const float* __restrict__ xg, const int* __restrict__ cls_g,
    const __bf16* __restrict__ wt, const float* __restrict__ bias,
    float* __restrict__ out) {
    __shared__ __align__(16) __bf16 ldsA[128 * CINX];   // 32 KB
    __shared__ __align__(16) __bf16 ldsB[FOUT * CINX];  // 64 KB

    const int bid = blockIdx.x;
    const int b   = bid >> 5;   // sample
    const int pt  = bid & 31;   // pixel tile (2 image rows)
    const int cls = cls_g[b];

    const int tid  = threadIdx.x;
    const int lane = tid & 63;
    const int wid  = tid >> 6;   // 0..7
    const int wm   = wid >> 2;   // 0..1
    const int wn   = wid & 3;    // 0..3

    f32x4 acc[4][4];
#pragma unroll
    for (int i = 0; i < 4; ++i)
#pragma unroll
        for (int j = 0; j < 4; ++j)
#pragma unroll
            for (int r = 0; r < 4; ++r) acc[i][j][r] = 0.f;

    // A-staging coords: 4 threads per pixel, 32 c each
    const int ap  = tid >> 2;          // pixel in tile, 0..127
    const int acq = tid & 3;           // c-quarter
    const int ay  = (pt << 1) + (ap >> 6);
    const int ax  = ap & 63;
    const float* xb = xg + (size_t)b * (HH * WW * CINX);

    const int l15 = lane & 15;
    const int l4  = lane >> 4;

    for (int t9 = 0; t9 < 9; ++t9) {
        const int ky = t9 / 3, kx = t9 % 3;

        // ---- stage A (shifted pixels, zero pad at borders) ----
        {
            const int gy = ay + ky - 1;
            const int gx = ax + kx - 1;
            const bool valid = ((unsigned)gy < 64u) && ((unsigned)gx < 64u);
            const float* src = xb + ((size_t)(gy * 64 + gx)) * CINX + acq * 32;
            __bf16* ldsrow = ldsA + ap * CINX;
#pragma unroll
            for (int j = 0; j < 4; ++j) {
                bf16x8 pk;
                if (valid) {
                    f32x4 v0 = *(const f32x4*)(src + j * 8);
                    f32x4 v1 = *(const f32x4*)(src + j * 8 + 4);
#pragma unroll
                    for (int q = 0; q < 4; ++q) {
                        pk[q]     = (__bf16)v0[q];
                        pk[4 + q] = (__bf16)v1[q];
                    }
                } else {
#pragma unroll
                    for (int q = 0; q < 8; ++q) pk[q] = (__bf16)0.f;
                }
                const int u = (acq * 4 + j) ^ (ap & 7);   // swizzled 16B unit
                *(bf16x8*)(ldsrow + u * 8) = pk;
            }
        }

        // ---- stage B (bf16 [f][c], coalesced 16B, swizzled write) ----
        {
            const __bf16* wsrc = wt + (size_t)(cls * 9 + t9) * (FOUT * CINX);
#pragma unroll
            for (int i = 0; i < 8; ++i) {
                const int g  = tid + i * 512;   // 16B unit, 0..4095
                const int f  = g >> 4;
                const int cu = g & 15;
                bf16x8 v = *(const bf16x8*)(wsrc + (size_t)g * 8);
                const int cu2 = cu ^ (f & 7);
                *(bf16x8*)(ldsB + f * CINX + cu2 * 8) = v;
            }
        }

        __syncthreads();

        // ---- compute: 4 k-chunks x (4 mt x 4 nt) MFMA ----
#pragma unroll
        for (int kk = 0; kk < 4; ++kk) {
            bf16x8 afr[4], bfr[4];
#pragma unroll
            for (int mt = 0; mt < 4; ++mt) {
                const int row = wm * 64 + mt * 16 + l15;
                const int u   = (kk * 4 + l4) ^ (row & 7);
                afr[mt] = *(const bf16x8*)(ldsA + row * CINX + u * 8);
            }
#pragma unroll
            for (int nt = 0; nt < 4; ++nt) {
                const int row = wn * 64 + nt * 16 + l15;
                const int u   = (kk * 4 + l4) ^ (row & 7);
                bfr[nt] = *(const bf16x8*)(ldsB + row * CINX + u * 8);
            }
#pragma unroll
            for (int mt = 0; mt < 4; ++mt)
#pragma unroll
                for (int nt = 0; nt < 4; ++nt)
                    acc[mt][nt] = __builtin_amdgcn_mfma_f32_16x16x32_bf16(
                        afr[mt], bfr[nt], acc[mt][nt], 0, 0, 0);
        }

        __syncthreads();
    }

    // ---- epilogue: bias + store f32 ----
    float bv[4];
#pragma unroll
    for (int nt = 0; nt < 4; ++nt)
        bv[nt] = bias[cls * FOUT + wn * 64 + nt * 16 + l15];

    float* ob = out + ((size_t)b * 4096 + (size_t)pt * 128) * FOUT;
#pragma unroll
    for (int mt = 0; mt < 4; ++mt) {
#pragma unroll
        for (int r = 0; r < 4; ++r) {
            const int row = wm * 64 + mt * 16 + l4 * 4 + r;
            float* orow = ob + (size_t)row * FOUT;
#pragma unroll
            for (int nt = 0; nt < 4; ++nt) {
                orow[wn * 64 + nt * 16 + l15] = acc[mt][nt][r] + bv[nt];
            }
        }
    }
}

extern "C" void kernel_launch(void* const* d_in, const int* in_sizes, int n_in,
                              void* d_out, int out_size, void* d_ws, size_t ws_size,
                              hipStream_t stream) {
    const float* x       = (const float*)d_in[0];
    const int*   classes = (const int*)d_in[1];
    const float* kin     = (const float*)d_in[2];
    const float* bias    = (const float*)d_in[3];
    float* out = (float*)d_out;
    __bf16* wt = (__bf16*)d_ws;   // 10*9*256*128*2 = 5.9 MB scratch

    prep_weights<<<dim3(NCLS * 9), dim3(256), 0, stream>>>(kin, wt);
    conv_main<<<dim3(BATCH * 32), dim3(512), 0, stream>>>(x, classes, wt, bias, out);
}

// Round 2
// 138.602 us; speedup vs baseline: 1.2667x; 1.2667x over previous
//
#include <hip/hip_runtime.h>
#include <stdint.h>

#define BATCH 32
#define HH 64
#define WW 64
#define CINX 128
#define FOUT 256
#define NCLS 10
#define NSTEP 18   // 9 taps x 2 c-halves of 64

typedef __bf16 bf16x8 __attribute__((ext_vector_type(8)));
typedef float f32x4 __attribute__((ext_vector_type(4)));

__device__ __forceinline__ void gload_lds16(const __bf16* g, __bf16* l) {
    __builtin_amdgcn_global_load_lds(
        (const __attribute__((address_space(1))) void*)g,
        (__attribute__((address_space(3))) void*)l, 16, 0, 0);
}

// ---------------------------------------------------------------------------
// Prep: kernel [cls][ky][kx][c][f] f32 -> wt [slab][c/8][f][8c] bf16
// (c-chunked so main-kernel B staging is a linear 16B-unit copy and B
//  fragment reads are lane-consecutive -> conflict-free, no swizzle)
// ---------------------------------------------------------------------------
__global__ __launch_bounds__(256) void prep_weights(const float* __restrict__ kin,
                                                    __bf16* __restrict__ wt) {
    __shared__ __bf16 tile[128 * 260];
    const int slab = blockIdx.x;  // 0..89
    const float* src = kin + (size_t)slab * (CINX * FOUT);
    __bf16* dst = wt + (size_t)slab * (16 * 256 * 8);
    const int t = threadIdx.x;

#pragma unroll
    for (int i = 0; i < 32; ++i) {
        int e4 = t + i * 256;      // float4 index over [c][f]
        int c  = e4 >> 6;
        int f4 = e4 & 63;
        f32x4 v = *(const f32x4*)(src + (size_t)e4 * 4);
        __bf16* p = &tile[c * 260 + f4 * 4];
        p[0] = (__bf16)v[0]; p[1] = (__bf16)v[1];
        p[2] = (__bf16)v[2]; p[3] = (__bf16)v[3];
    }
    __syncthreads();
    // dest 16B unit g: cu = g>>8, f = g&255, holds c = cu*8..cu*8+7 at fixed f
#pragma unroll
    for (int i = 0; i < 16; ++i) {
        int g  = t + i * 256;
        int cu = g >> 8;
        int f  = g & 255;
        bf16x8 o;
#pragma unroll
        for (int j = 0; j < 8; ++j) o[j] = tile[(cu * 8 + j) * 260 + f];
        *(bf16x8*)(dst + (size_t)g * 8) = o;
    }
}

// ---------------------------------------------------------------------------
// Main: implicit-GEMM conv, m201-style geometry.
// Block = 256 px (4 image rows) x 256 f, BK=64, 18 K-steps, 8 waves (2Mx4N),
// per-wave 128x64 output. LDS [buf][cu][row][8c] for A and B, double-buffered
// (128 KB). 2-phase pipeline: prefetch (B via global_load_lds, A via f32
// regs) overlaps MFMA; A convert+ds_write after compute; 1 barrier/step.
// ---------------------------------------------------------------------------
__global__ __launch_bounds__(512, 2) void conv_main(
    const float* __restrict__ xg, const int* __restrict__ cls_g,
    const __bf16* __restrict__ wt, const float* __restrict__ bias,
    float* __restrict__ out) {
    __shared__ __align__(16) __bf16 ldsA[2][8 * 256 * 8];  // 64 KB
    __shared__ __align__(16) __bf16 ldsB[2][8 * 256 * 8];  // 64 KB

    // XCD-aware swizzle (512 blocks, 512%8==0 -> bijective chunked map)
    const int bid0 = blockIdx.x;
    const int swz  = (bid0 & 7) * 64 + (bid0 >> 3);
    const int b    = swz >> 4;   // sample
    const int pt   = swz & 15;   // 4-row tile
    const int cls  = cls_g[b];
    const int y0   = pt << 2;

    const int tid  = threadIdx.x;
    const int lane = tid & 63;
    const int wid  = tid >> 6;
    const int wm   = wid >> 2;   // 0..1
    const int wn   = wid & 3;    // 0..3
    const int l15  = lane & 15;
    const int l4   = lane >> 4;

    const float* xb = xg + (size_t)b * (HH * WW * CINX);
    const __bf16* wcls = wt + (size_t)cls * 9 * (16 * 256 * 8);

    // A staging: thread t -> pixel t>>1, c-offset (t&1)*32 within the 64-c step
    const int tpx = tid >> 1;
    const int tch = (tid & 1) * 32;
    const int py  = tpx >> 6;     // 0..3
    const int px_ = tpx & 63;

    f32x4 acc[8][4];
#pragma unroll
    for (int i = 0; i < 8; ++i)
#pragma unroll
        for (int j = 0; j < 4; ++j)
#pragma unroll
            for (int r = 0; r < 4; ++r) acc[i][j][r] = 0.f;

    f32x4 va[8];

    auto issueB = [&](int s, int buf) {
        const int tap = s >> 1, chalf = (s & 1) << 6;
        const __bf16* wsrc = wcls + (size_t)tap * (16 * 256 * 8) + chalf * 256;
#pragma unroll
        for (int i = 0; i < 4; ++i) {
            const int u = i * 512 + tid;
            gload_lds16(wsrc + (size_t)u * 8, &ldsB[buf][(size_t)u * 8]);
        }
    };

    auto issueA = [&](int s) {
        const int tap = s >> 1, chalf = (s & 1) << 6;
        const int dy = tap / 3 - 1, dx = tap % 3 - 1;
        const int gy = y0 + py + dy;
        const int gx = px_ + dx;
        const bool valid = ((unsigned)gy < 64u) && ((unsigned)gx < 64u);
        const float* src = xb + ((size_t)(gy * 64 + gx)) * CINX + chalf + tch;
        if (valid) {
#pragma unroll
            for (int j2 = 0; j2 < 8; ++j2) va[j2] = *(const f32x4*)(src + j2 * 4);
        } else {
#pragma unroll
            for (int j2 = 0; j2 < 8; ++j2)
#pragma unroll
                for (int q = 0; q < 4; ++q) va[j2][q] = 0.f;
        }
    };

    auto writeA = [&](int buf) {
#pragma unroll
        for (int j = 0; j < 4; ++j) {
            bf16x8 pk;
#pragma unroll
            for (int q = 0; q < 4; ++q) {
                pk[q]     = (__bf16)va[2 * j][q];
                pk[4 + q] = (__bf16)va[2 * j + 1][q];
            }
            const int u = ((tid & 1) * 4 + j) * 256 + tpx;
            *(bf16x8*)(&ldsA[buf][(size_t)u * 8]) = pk;
        }
    };

    auto compute = [&](int buf) {
#pragma unroll
        for (int kk = 0; kk < 2; ++kk) {
            const int cu = kk * 4 + l4;
            bf16x8 afr[8], bfr[4];
#pragma unroll
            for (int mt = 0; mt < 8; ++mt)
                afr[mt] = *(const bf16x8*)(
                    &ldsA[buf][(size_t)(cu * 256 + wm * 128 + mt * 16 + l15) * 8]);
#pragma unroll
            for (int nt = 0; nt < 4; ++nt)
                bfr[nt] = *(const bf16x8*)(
                    &ldsB[buf][(size_t)(cu * 256 + wn * 64 + nt * 16 + l15) * 8]);
#pragma unroll
            for (int mt = 0; mt < 8; ++mt)
#pragma unroll
                for (int nt = 0; nt < 4; ++nt)
                    acc[mt][nt] = __builtin_amdgcn_mfma_f32_16x16x32_bf16(
                        afr[mt], bfr[nt], acc[mt][nt], 0, 0, 0);
        }
    };

    // prologue: stage step 0 into buf 0
    issueB(0, 0);
    issueA(0);
    writeA(0);
    __syncthreads();

    int cur = 0;
    for (int s = 0; s < NSTEP - 1; ++s) {
        issueB(s + 1, cur ^ 1);   // async -> LDS, in flight across compute
        issueA(s + 1);            // f32 -> regs, latency under MFMA
        compute(cur);
        writeA(cur ^ 1);          // waits va, converts, ds_write
        __syncthreads();          // drains gload_lds + ds_writes; frees cur
        cur ^= 1;
    }
    compute(cur);

    // ---- epilogue: bias + f32 store ----
    float bv[4];
#pragma unroll
    for (int nt = 0; nt < 4; ++nt)
        bv[nt] = bias[cls * FOUT + wn * 64 + nt * 16 + l15];

    float* ob = out + ((size_t)b * 4096 + (size_t)pt * 256) * FOUT;
#pragma unroll
    for (int mt = 0; mt < 8; ++mt) {
#pragma unroll
        for (int r = 0; r < 4; ++r) {
            const int row = wm * 128 + mt * 16 + l4 * 4 + r;
            float* orow = ob + (size_t)row * FOUT;
#pragma unroll
            for (int nt = 0; nt < 4; ++nt)
                orow[wn * 64 + nt * 16 + l15] = acc[mt][nt][r] + bv[nt];
        }
    }
}

extern "C" void kernel_launch(void* const* d_in, const int* in_sizes, int n_in,
                              void* d_out, int out_size, void* d_ws, size_t ws_size,
                              hipStream_t stream) {
    const float* x       = (const float*)d_in[0];
    const int*   classes = (const int*)d_in[1];
    const float* kin     = (const float*)d_in[2];
    const float* bias    = (const float*)d_in[3];
    float* out = (float*)d_out;
    __bf16* wt = (__bf16*)d_ws;   // 90 slabs * 32768 bf16 = 5.9 MB

    prep_weights<<<dim3(NCLS * 9), dim3(256), 0, stream>>>(kin, wt);
    conv_main<<<dim3(512), dim3(512), 0, stream>>>(x, classes, wt, bias, out);
}

// Round 3
// 108.886 us; speedup vs baseline: 1.6125x; 1.2729x over previous
//
#include <hip/hip_runtime.h>
#include <stdint.h>

#define BATCH 32
#define CINX 128
#define FOUT 256
#define NCLS 10
#define NSTEP 18   // 9 taps x 2 c-halves of 64

typedef __bf16 bf16x8 __attribute__((ext_vector_type(8)));
typedef float f32x4 __attribute__((ext_vector_type(4)));

#define WT_SLAB 32768                                  // bf16 per (cls,tap)
#define WT_BYTES ((size_t)NCLS * 9 * WT_SLAB * 2)      // 5,898,240
#define Z_BYTES 4096
#define X16_BYTES ((size_t)BATCH * 4096 * CINX * 2)    // 33,554,432
#define WS_NEED (WT_BYTES + Z_BYTES + X16_BYTES)

#define BAR() __builtin_amdgcn_s_barrier()
#define VMW4() asm volatile("s_waitcnt vmcnt(4)" ::: "memory")
#define VMW0() asm volatile("s_waitcnt vmcnt(0)" ::: "memory")

__device__ __forceinline__ void gl16(const __bf16* g, __bf16* l) {
    __builtin_amdgcn_global_load_lds(
        (const __attribute__((address_space(1))) void*)g,
        (__attribute__((address_space(3))) void*)l, 16, 0, 0);
}

// ---------------------------------------------------------------------------
// prep_w8: kernel [cls][tap][c][f] f32 -> wt [slab][h=c/32][f][slot] bf16,
// pre-swizzled: unit (f,slot) holds c-chunk cu = slot ^ ((f>>1)&3) of half h.
// ---------------------------------------------------------------------------
__global__ __launch_bounds__(256) void prep_w8(const float* __restrict__ kin,
                                               __bf16* __restrict__ wt) {
    __shared__ __bf16 tile[128 * 260];
    const int slab = blockIdx.x;  // 0..89
    const float* src = kin + (size_t)slab * (CINX * FOUT);
    __bf16* dst = wt + (size_t)slab * WT_SLAB;
    const int t = threadIdx.x;
#pragma unroll
    for (int i = 0; i < 32; ++i) {
        int e4 = t + i * 256;
        int c = e4 >> 6, f4 = e4 & 63;
        f32x4 v = *(const f32x4*)(src + (size_t)e4 * 4);
        __bf16* p = &tile[c * 260 + f4 * 4];
        p[0] = (__bf16)v[0]; p[1] = (__bf16)v[1];
        p[2] = (__bf16)v[2]; p[3] = (__bf16)v[3];
    }
    __syncthreads();
#pragma unroll
    for (int i = 0; i < 16; ++i) {
        int g = t + i * 256;          // 16B unit within slab, 0..4095
        int h = g >> 10;              // 32-c half image
        int u = g & 1023;
        int f = u >> 2, slot = u & 3;
        int cu = slot ^ ((f >> 1) & 3);
        int c0 = h * 32 + cu * 8;
        bf16x8 o;
#pragma unroll
        for (int j = 0; j < 8; ++j) o[j] = tile[(c0 + j) * 260 + f];
        *(bf16x8*)(dst + (size_t)g * 8) = o;
    }
}

// ---------------------------------------------------------------------------
// prep_x: x f32 [b][px][c] -> bf16 same layout; also zero the pad slab.
// ---------------------------------------------------------------------------
__global__ __launch_bounds__(256) void prep_x(const float* __restrict__ x,
                                              __bf16* __restrict__ x16,
                                              __bf16* __restrict__ zbuf) {
    const size_t u = (size_t)blockIdx.x * 256 + threadIdx.x;  // 8-elem unit
    f32x4 a = *(const f32x4*)(x + u * 8);
    f32x4 c = *(const f32x4*)(x + u * 8 + 4);
    bf16x8 o;
#pragma unroll
    for (int j = 0; j < 4; ++j) { o[j] = (__bf16)a[j]; o[4 + j] = (__bf16)c[j]; }
    *(bf16x8*)(x16 + u * 8) = o;
    if (blockIdx.x == 0 && threadIdx.x < 128) {
        bf16x8 z;
#pragma unroll
        for (int j = 0; j < 8; ++j) z[j] = (__bf16)0.f;
        *(bf16x8*)(zbuf + (size_t)threadIdx.x * 8) = z;
    }
}

// ---------------------------------------------------------------------------
// conv_main8: 256px x 256f tile, BK=64 split into 2x32-c halves, 18 K-steps,
// 8 waves (2Mx4N), per-wave 128x64 out. Quad-buffered LDS (parity x kk),
// 4 phases/step, counted vmcnt(4) (never drains to 0 in main loop), raw
// s_barrier pairs, setprio around MFMA clusters. All staging via gload_lds.
// ---------------------------------------------------------------------------
__global__ __launch_bounds__(512, 2) void conv_main8(
    const __bf16* __restrict__ xg16, const int* __restrict__ cls_g,
    const __bf16* __restrict__ wt, const float* __restrict__ bias,
    const __bf16* __restrict__ zbuf, float* __restrict__ out) {
    __shared__ __align__(16) __bf16 ldsA[2][2][1024 * 8];  // 64 KB
    __shared__ __align__(16) __bf16 ldsB[2][2][1024 * 8];  // 64 KB

    const int bid0 = blockIdx.x;
    const int swz  = (bid0 & 7) * 64 + (bid0 >> 3);   // XCD swizzle, bijective
    const int b    = swz >> 4;
    const int pt   = swz & 15;
    const int cls  = cls_g[b];
    const int y0   = pt << 2;

    const int tid  = threadIdx.x;
    const int lane = tid & 63;
    const int wid  = tid >> 6;
    const int wm   = wid >> 2;   // 0..1
    const int wn   = wid & 3;    // 0..3
    const int l15  = lane & 15;
    const int l4   = lane >> 4;

    const __bf16* xb   = xg16 + (size_t)b * 4096 * CINX;
    const __bf16* wcls = wt + (size_t)cls * 9 * WT_SLAB;

    // ---- loop-invariant staging coords (i=0,1 -> unit u = i*512+tid) ----
    int pyA[2], gxA[2], cuoffA[2], uS[2];
#pragma unroll
    for (int i = 0; i < 2; ++i) {
        int u = i * 512 + tid;
        int px = u >> 2, slot = u & 3;
        uS[i] = u;
        pyA[i] = px >> 6;
        gxA[i] = px & 63;
        cuoffA[i] = (slot ^ ((px >> 1) & 3)) * 8;
    }
    // ---- loop-invariant fragment-read units ----
    int unA[8], unB[4];
#pragma unroll
    for (int mt = 0; mt < 8; ++mt) {
        int px = wm * 128 + mt * 16 + l15;
        unA[mt] = px * 4 + (l4 ^ ((px >> 1) & 3));
    }
#pragma unroll
    for (int nt = 0; nt < 4; ++nt) {
        int f = wn * 64 + nt * 16 + l15;
        unB[nt] = f * 4 + (l4 ^ ((f >> 1) & 3));
    }

    f32x4 acc[8][4];
#pragma unroll
    for (int i = 0; i < 8; ++i)
#pragma unroll
        for (int j = 0; j < 4; ++j)
#pragma unroll
            for (int r = 0; r < 4; ++r) acc[i][j][r] = 0.f;

    // stage one 32-c half of step s2 (4 gload_lds/thread: 2 A + 2 B)
    auto stage = [&](int s2, int kk) {
        const int p = s2 & 1;
        const int tap = s2 >> 1;
        const int dy = tap / 3 - 1, dx = tap % 3 - 1;
        const int choff = (s2 & 1) * 64 + kk * 32;
#pragma unroll
        for (int i = 0; i < 2; ++i) {
            const int gy = y0 + pyA[i] + dy;
            const int gx = gxA[i] + dx;
            const bool v = ((unsigned)gy < 64u) && ((unsigned)gx < 64u);
            const __bf16* src = v
                ? (xb + ((size_t)(gy * 64 + gx)) * CINX + choff + cuoffA[i])
                : (zbuf + (size_t)(uS[i] & 63) * 8);
            gl16(src, &ldsA[p][kk][(size_t)uS[i] * 8]);
        }
        const __bf16* wsrc = wcls + (size_t)tap * WT_SLAB +
                             (size_t)((s2 & 1) * 2 + kk) * 8192;
#pragma unroll
        for (int i = 0; i < 2; ++i)
            gl16(wsrc + (size_t)uS[i] * 8, &ldsB[p][kk][(size_t)uS[i] * 8]);
    };

    bf16x8 afr[4], bfr[4];
    auto ldB = [&](int p, int kk) {
#pragma unroll
        for (int nt = 0; nt < 4; ++nt)
            bfr[nt] = *(const bf16x8*)&ldsB[p][kk][(size_t)unB[nt] * 8];
    };
    auto ldA = [&](int p, int kk, int mh) {
#pragma unroll
        for (int mt = 0; mt < 4; ++mt)
            afr[mt] = *(const bf16x8*)&ldsA[p][kk][(size_t)unA[mh * 4 + mt] * 8];
    };
    auto mm = [&](int mh) {
        __builtin_amdgcn_s_setprio(1);
#pragma unroll
        for (int mt = 0; mt < 4; ++mt)
#pragma unroll
            for (int nt = 0; nt < 4; ++nt)
                acc[mh * 4 + mt][nt] = __builtin_amdgcn_mfma_f32_16x16x32_bf16(
                    afr[mt], bfr[nt], acc[mh * 4 + mt][nt], 0, 0, 0);
        __builtin_amdgcn_s_setprio(0);
    };

    // prologue: both halves of step 0 in flight; land k0, keep k1 flying
    stage(0, 0);
    stage(0, 1);
    VMW4();
    BAR();

    for (int s = 0; s < NSTEP - 1; ++s) {
        const int p = s & 1;
        // ph0: compute (k0, mh0); issue next-step k0
        ldB(p, 0); ldA(p, 0, 0); stage(s + 1, 0);
        BAR(); mm(0); BAR();
        // ph1: compute (k0, mh1); land [s,k1] (leaves [s+1,k0] in flight)
        ldA(p, 0, 1);
        VMW4();
        BAR(); mm(1); BAR();
        // ph2: compute (k1, mh0); issue next-step k1
        ldB(p, 1); ldA(p, 1, 0); stage(s + 1, 1);
        BAR(); mm(0); BAR();
        // ph3: compute (k1, mh1); land [s+1,k0] (leaves [s+1,k1] in flight)
        ldA(p, 1, 1);
        VMW4();
        BAR(); mm(1); BAR();
    }
    // peeled last step (s = 17, p = 1): drain instead of count
    ldB(1, 0); ldA(1, 0, 0);
    BAR(); mm(0); BAR();
    ldA(1, 0, 1);
    VMW0();
    BAR(); mm(1); BAR();
    ldB(1, 1); ldA(1, 1, 0);
    BAR(); mm(0); BAR();
    ldA(1, 1, 1);
    mm(1);

    // ---- epilogue: bias + f32 store ----
    float bv[4];
#pragma unroll
    for (int nt = 0; nt < 4; ++nt)
        bv[nt] = bias[cls * FOUT + wn * 64 + nt * 16 + l15];

    float* ob = out + ((size_t)b * 4096 + (size_t)pt * 256) * FOUT;
#pragma unroll
    for (int mt = 0; mt < 8; ++mt) {
#pragma unroll
        for (int r = 0; r < 4; ++r) {
            const int row = wm * 128 + mt * 16 + l4 * 4 + r;
            float* orow = ob + (size_t)row * FOUT;
#pragma unroll
            for (int nt = 0; nt < 4; ++nt)
                orow[wn * 64 + nt * 16 + l15] = acc[mt][nt][r] + bv[nt];
        }
    }
}

// ===========================================================================
// Fallback path (round-2 kernels) if ws_size < WS_NEED
// ===========================================================================
__global__ __launch_bounds__(256) void prep_w_fb(const float* __restrict__ kin,
                                                 __bf16* __restrict__ wt) {
    __shared__ __bf16 tile[128 * 260];
    const int slab = blockIdx.x;
    const float* src = kin + (size_t)slab * (CINX * FOUT);
    __bf16* dst = wt + (size_t)slab * (16 * 256 * 8);
    const int t = threadIdx.x;
#pragma unroll
    for (int i = 0; i < 32; ++i) {
        int e4 = t + i * 256;
        int c = e4 >> 6, f4 = e4 & 63;
        f32x4 v = *(const f32x4*)(src + (size_t)e4 * 4);
        __bf16* p = &tile[c * 260 + f4 * 4];
        p[0] = (__bf16)v[0]; p[1] = (__bf16)v[1];
        p[2] = (__bf16)v[2]; p[3] = (__bf16)v[3];
    }
    __syncthreads();
#pragma unroll
    for (int i = 0; i < 16; ++i) {
        int g = t + i * 256;
        int cu = g >> 8, f = g & 255;
        bf16x8 o;
#pragma unroll
        for (int j = 0; j < 8; ++j) o[j] = tile[(cu * 8 + j) * 260 + f];
        *(bf16x8*)(dst + (size_t)g * 8) = o;
    }
}

__global__ __launch_bounds__(512, 2) void conv_fb(
    const float* __restrict__ xg, const int* __restrict__ cls_g,
    const __bf16* __restrict__ wt, const float* __restrict__ bias,
    float* __restrict__ out) {
    __shared__ __align__(16) __bf16 ldsA[2][8 * 256 * 8];
    __shared__ __align__(16) __bf16 ldsB[2][8 * 256 * 8];
    const int bid0 = blockIdx.x;
    const int swz = (bid0 & 7) * 64 + (bid0 >> 3);
    const int b = swz >> 4, pt = swz & 15;
    const int cls = cls_g[b];
    const int y0 = pt << 2;
    const int tid = threadIdx.x, lane = tid & 63, wid = tid >> 6;
    const int wm = wid >> 2, wn = wid & 3, l15 = lane & 15, l4 = lane >> 4;
    const float* xb = xg + (size_t)b * 4096 * CINX;
    const __bf16* wcls = wt + (size_t)cls * 9 * (16 * 256 * 8);
    const int tpx = tid >> 1, tch = (tid & 1) * 32;
    const int py = tpx >> 6, px_ = tpx & 63;
    f32x4 acc[8][4];
#pragma unroll
    for (int i = 0; i < 8; ++i)
#pragma unroll
        for (int j = 0; j < 4; ++j)
#pragma unroll
            for (int r = 0; r < 4; ++r) acc[i][j][r] = 0.f;
    f32x4 va[8];
    auto issueB = [&](int s, int buf) {
        const int tap = s >> 1, chalf = (s & 1) << 6;
        const __bf16* wsrc = wcls + (size_t)tap * (16 * 256 * 8) + chalf * 256;
#pragma unroll
        for (int i = 0; i < 4; ++i) {
            const int u = i * 512 + tid;
            gl16(wsrc + (size_t)u * 8, &ldsB[buf][(size_t)u * 8]);
        }
    };
    auto issueA = [&](int s) {
        const int tap = s >> 1, chalf = (s & 1) << 6;
        const int dy = tap / 3 - 1, dx = tap % 3 - 1;
        const int gy = y0 + py + dy, gx = px_ + dx;
        const bool valid = ((unsigned)gy < 64u) && ((unsigned)gx < 64u);
        const float* src = xb + ((size_t)(gy * 64 + gx)) * CINX + chalf + tch;
        if (valid) {
#pragma unroll
            for (int j2 = 0; j2 < 8; ++j2) va[j2] = *(const f32x4*)(src + j2 * 4);
        } else {
#pragma unroll
            for (int j2 = 0; j2 < 8; ++j2)
#pragma unroll
                for (int q = 0; q < 4; ++q) va[j2][q] = 0.f;
        }
    };
    auto writeA = [&](int buf) {
#pragma unroll
        for (int j = 0; j < 4; ++j) {
            bf16x8 pk;
#pragma unroll
            for (int q = 0; q < 4; ++q) {
                pk[q] = (__bf16)va[2 * j][q];
                pk[4 + q] = (__bf16)va[2 * j + 1][q];
            }
            const int u = ((tid & 1) * 4 + j) * 256 + tpx;
            *(bf16x8*)(&ldsA[buf][(size_t)u * 8]) = pk;
        }
    };
    auto compute = [&](int buf) {
#pragma unroll
        for (int kk = 0; kk < 2; ++kk) {
            const int cu = kk * 4 + l4;
            bf16x8 afr[8], bfr[4];
#pragma unroll
            for (int mt = 0; mt < 8; ++mt)
                afr[mt] = *(const bf16x8*)(
                    &ldsA[buf][(size_t)(cu * 256 + wm * 128 + mt * 16 + l15) * 8]);
#pragma unroll
            for (int nt = 0; nt < 4; ++nt)
                bfr[nt] = *(const bf16x8*)(
                    &ldsB[buf][(size_t)(cu * 256 + wn * 64 + nt * 16 + l15) * 8]);
#pragma unroll
            for (int mt = 0; mt < 8; ++mt)
#pragma unroll
                for (int nt = 0; nt < 4; ++nt)
                    acc[mt][nt] = __builtin_amdgcn_mfma_f32_16x16x32_bf16(
                        afr[mt], bfr[nt], acc[mt][nt], 0, 0, 0);
        }
    };
    issueB(0, 0);
    issueA(0);
    writeA(0);
    __syncthreads();
    int cur = 0;
    for (int s = 0; s < NSTEP - 1; ++s) {
        issueB(s + 1, cur ^ 1);
        issueA(s + 1);
        compute(cur);
        writeA(cur ^ 1);
        __syncthreads();
        cur ^= 1;
    }
    compute(cur);
    float bv[4];
#pragma unroll
    for (int nt = 0; nt < 4; ++nt)
        bv[nt] = bias[cls * FOUT + wn * 64 + nt * 16 + l15];
    float* ob = out + ((size_t)b * 4096 + (size_t)pt * 256) * FOUT;
#pragma unroll
    for (int mt = 0; mt < 8; ++mt) {
#pragma unroll
        for (int r = 0; r < 4; ++r) {
            const int row = wm * 128 + mt * 16 + l4 * 4 + r;
            float* orow = ob + (size_t)row * FOUT;
#pragma unroll
            for (int nt = 0; nt < 4; ++nt)
                orow[wn * 64 + nt * 16 + l15] = acc[mt][nt][r] + bv[nt];
        }
    }
}

extern "C" void kernel_launch(void* const* d_in, const int* in_sizes, int n_in,
                              void* d_out, int out_size, void* d_ws, size_t ws_size,
                              hipStream_t stream) {
    const float* x       = (const float*)d_in[0];
    const int*   classes = (const int*)d_in[1];
    const float* kin     = (const float*)d_in[2];
    const float* bias    = (const float*)d_in[3];
    float* out = (float*)d_out;

    char* ws = (char*)d_ws;
    __bf16* wt   = (__bf16*)ws;
    __bf16* zbuf = (__bf16*)(ws + WT_BYTES);
    __bf16* x16  = (__bf16*)(ws + WT_BYTES + Z_BYTES);

    if (ws_size >= WS_NEED) {
        prep_w8<<<dim3(NCLS * 9), dim3(256), 0, stream>>>(kin, wt);
        prep_x<<<dim3(8192), dim3(256), 0, stream>>>(x, x16, zbuf);
        conv_main8<<<dim3(512), dim3(512), 0, stream>>>(x16, classes, wt, bias,
                                                        zbuf, out);
    } else {
        prep_w_fb<<<dim3(NCLS * 9), dim3(256), 0, stream>>>(kin, wt);
        conv_fb<<<dim3(512), dim3(512), 0, stream>>>(x, classes, wt, bias, out);
    }
}

// Round 4
// 101.729 us; speedup vs baseline: 1.7259x; 1.0704x over previous
//
#include <hip/hip_runtime.h>
#include <stdint.h>

#define BATCH 32
#define CINX 128
#define FOUT 256
#define NCLS 10
#define NSTEP 18   // 9 taps x 2 c-halves of 64

typedef __bf16 bf16x8 __attribute__((ext_vector_type(8)));
typedef float f32x4 __attribute__((ext_vector_type(4)));

#define WT_SLAB 32768                                  // bf16 per (cls,tap)
#define WT_BYTES ((size_t)NCLS * 9 * WT_SLAB * 2)      // 5,898,240
#define Z_BYTES 4096
#define X16_BYTES ((size_t)BATCH * 4096 * CINX * 2)    // 33,554,432
#define WS_NEED (WT_BYTES + Z_BYTES + X16_BYTES)

#define BAR() __builtin_amdgcn_s_barrier()
#define SCHEDBAR() __builtin_amdgcn_sched_barrier(0)
#define VMW4() asm volatile("s_waitcnt vmcnt(4)" ::: "memory")
#define VMW0() asm volatile("s_waitcnt vmcnt(0)" ::: "memory")

__device__ __forceinline__ void gl16(const __bf16* g, __bf16* l) {
    __builtin_amdgcn_global_load_lds(
        (const __attribute__((address_space(1))) void*)g,
        (__attribute__((address_space(3))) void*)l, 16, 0, 0);
}

// ---------------------------------------------------------------------------
// prep_all: fused weight transpose+convert and x convert (one launch).
// blocks 0..89: kernel [cls][tap][c][f] f32 -> wt [slab][h=c/32][f][slot]
//   bf16, pre-swizzled (slot holds c-chunk cu = slot ^ ((f>>1)&3)).
// blocks 90.. : x f32 -> bf16 flat; block 90 also zeroes the pad slab.
// ---------------------------------------------------------------------------
__global__ __launch_bounds__(256) void prep_all(const float* __restrict__ kin,
                                                __bf16* __restrict__ wt,
                                                const float* __restrict__ x,
                                                __bf16* __restrict__ x16,
                                                __bf16* __restrict__ zbuf) {
    if (blockIdx.x < NCLS * 9) {
        __shared__ __bf16 tile[128 * 260];
        const int slab = blockIdx.x;
        const float* src = kin + (size_t)slab * (CINX * FOUT);
        __bf16* dst = wt + (size_t)slab * WT_SLAB;
        const int t = threadIdx.x;
#pragma unroll
        for (int i = 0; i < 32; ++i) {
            int e4 = t + i * 256;
            int c = e4 >> 6, f4 = e4 & 63;
            f32x4 v = *(const f32x4*)(src + (size_t)e4 * 4);
            __bf16* p = &tile[c * 260 + f4 * 4];
            p[0] = (__bf16)v[0]; p[1] = (__bf16)v[1];
            p[2] = (__bf16)v[2]; p[3] = (__bf16)v[3];
        }
        __syncthreads();
#pragma unroll
        for (int i = 0; i < 16; ++i) {
            int g = t + i * 256;          // 16B unit within slab
            int h = g >> 10;              // 32-c half
            int u = g & 1023;
            int f = u >> 2, slot = u & 3;
            int cu = slot ^ ((f >> 1) & 3);
            int c0 = h * 32 + cu * 8;
            bf16x8 o;
#pragma unroll
            for (int j = 0; j < 8; ++j) o[j] = tile[(c0 + j) * 260 + f];
            *(bf16x8*)(dst + (size_t)g * 8) = o;
        }
    } else {
        const int bx = blockIdx.x - NCLS * 9;
        const size_t u = (size_t)bx * 256 + threadIdx.x;  // 8-elem unit
        f32x4 a = *(const f32x4*)(x + u * 8);
        f32x4 c = *(const f32x4*)(x + u * 8 + 4);
        bf16x8 o;
#pragma unroll
        for (int j = 0; j < 4; ++j) { o[j] = (__bf16)a[j]; o[4 + j] = (__bf16)c[j]; }
        *(bf16x8*)(x16 + u * 8) = o;
        if (bx == 0 && threadIdx.x < 128) {
            bf16x8 z;
#pragma unroll
            for (int j = 0; j < 8; ++j) z[j] = (__bf16)0.f;
            *(bf16x8*)(zbuf + (size_t)threadIdx.x * 8) = z;
        }
    }
}

// ---------------------------------------------------------------------------
// conv_main8: 256px x 256f tile, BK=64 as 2x32-c halves, 18 K-steps, 8 waves
// (2Mx4N), per-wave 128x64 out. Quad-buffered LDS (parity x kk). Minimal
// barrier set: ONLY the two vmcnt(4)-publish barriers per step survive; all
// other barriers dropped so waves skew within a 2-phase window and LDS reads
// of one wave overlap MFMA of another. setprio(1) around MFMA clusters.
// ---------------------------------------------------------------------------
__global__ __launch_bounds__(512, 2) void conv_main8(
    const __bf16* __restrict__ xg16, const int* __restrict__ cls_g,
    const __bf16* __restrict__ wt, const float* __restrict__ bias,
    const __bf16* __restrict__ zbuf, float* __restrict__ out) {
    __shared__ __align__(16) __bf16 ldsA[2][2][1024 * 8];  // 64 KB
    __shared__ __align__(16) __bf16 ldsB[2][2][1024 * 8];  // 64 KB

    const int bid0 = blockIdx.x;
    const int swz  = (bid0 & 7) * 64 + (bid0 >> 3);   // XCD swizzle, bijective
    const int b    = swz >> 4;
    const int pt   = swz & 15;
    const int cls  = cls_g[b];
    const int y0   = pt << 2;

    const int tid  = threadIdx.x;
    const int lane = tid & 63;
    const int wid  = tid >> 6;
    const int wm   = wid >> 2;   // 0..1
    const int wn   = wid & 3;    // 0..3
    const int l15  = lane & 15;
    const int l4   = lane >> 4;

    const __bf16* xb   = xg16 + (size_t)b * 4096 * CINX;
    const __bf16* wcls = wt + (size_t)cls * 9 * WT_SLAB;

    // ---- loop-invariant staging coords (i=0,1 -> unit u = i*512+tid) ----
    int pyA[2], gxA[2], cuoffA[2], uS[2];
#pragma unroll
    for (int i = 0; i < 2; ++i) {
        int u = i * 512 + tid;
        int px = u >> 2, slot = u & 3;
        uS[i] = u;
        pyA[i] = px >> 6;
        gxA[i] = px & 63;
        cuoffA[i] = (slot ^ ((px >> 1) & 3)) * 8;
    }
    // ---- loop-invariant fragment-read units ----
    int unA[8], unB[4];
#pragma unroll
    for (int mt = 0; mt < 8; ++mt) {
        int px = wm * 128 + mt * 16 + l15;
        unA[mt] = px * 4 + (l4 ^ ((px >> 1) & 3));
    }
#pragma unroll
    for (int nt = 0; nt < 4; ++nt) {
        int f = wn * 64 + nt * 16 + l15;
        unB[nt] = f * 4 + (l4 ^ ((f >> 1) & 3));
    }

    f32x4 acc[8][4];
#pragma unroll
    for (int i = 0; i < 8; ++i)
#pragma unroll
        for (int j = 0; j < 4; ++j)
#pragma unroll
            for (int r = 0; r < 4; ++r) acc[i][j][r] = 0.f;

    // stage one 32-c half of step s2 (4 gload_lds/thread: 2 A + 2 B)
    auto stage = [&](int s2, int kk) {
        const int p = s2 & 1;
        const int tap = s2 >> 1;
        const int dy = tap / 3 - 1, dx = tap % 3 - 1;
        const int choff = (s2 & 1) * 64 + kk * 32;
#pragma unroll
        for (int i = 0; i < 2; ++i) {
            const int gy = y0 + pyA[i] + dy;
            const int gx = gxA[i] + dx;
            const bool v = ((unsigned)gy < 64u) && ((unsigned)gx < 64u);
            const __bf16* src = v
                ? (xb + ((size_t)(gy * 64 + gx)) * CINX + choff + cuoffA[i])
                : (zbuf + (size_t)(uS[i] & 63) * 8);
            gl16(src, &ldsA[p][kk][(size_t)uS[i] * 8]);
        }
        const __bf16* wsrc = wcls + (size_t)tap * WT_SLAB +
                             (size_t)((s2 & 1) * 2 + kk) * 8192;
#pragma unroll
        for (int i = 0; i < 2; ++i)
            gl16(wsrc + (size_t)uS[i] * 8, &ldsB[p][kk][(size_t)uS[i] * 8]);
    };

    bf16x8 afr[4], bfr[4];
    auto ldB = [&](int p, int kk) {
#pragma unroll
        for (int nt = 0; nt < 4; ++nt)
            bfr[nt] = *(const bf16x8*)&ldsB[p][kk][(size_t)unB[nt] * 8];
    };
    auto ldA = [&](int p, int kk, int mh) {
#pragma unroll
        for (int mt = 0; mt < 4; ++mt)
            afr[mt] = *(const bf16x8*)&ldsA[p][kk][(size_t)unA[mh * 4 + mt] * 8];
    };
    auto mm = [&](int mh) {
        __builtin_amdgcn_s_setprio(1);
#pragma unroll
        for (int mt = 0; mt < 4; ++mt)
#pragma unroll
            for (int nt = 0; nt < 4; ++nt)
                acc[mh * 4 + mt][nt] = __builtin_amdgcn_mfma_f32_16x16x32_bf16(
                    afr[mt], bfr[nt], acc[mh * 4 + mt][nt], 0, 0, 0);
        __builtin_amdgcn_s_setprio(0);
    };

    // prologue: both halves of step 0 in flight; land k0 (publish), k1 flying
    stage(0, 0);
    stage(0, 1);
    VMW4();
    BAR();
    SCHEDBAR();

    for (int s = 0; s < NSTEP - 1; ++s) {
        const int p = s & 1;
        // ph0: reads of [p][0]; issue next-step k0; compute mh0
        ldB(p, 0); ldA(p, 0, 0); stage(s + 1, 0);
        mm(0);
        // ph1: land [s,k1] (leaves [s+1,k0] flying); publish; compute mh1
        ldA(p, 0, 1);
        VMW4();
        BAR();
        SCHEDBAR();
        mm(1);
        // ph2: reads of [p][1]; issue next-step k1; compute mh0
        ldB(p, 1); ldA(p, 1, 0); stage(s + 1, 1);
        mm(0);
        // ph3: land [s+1,k0]; publish; compute mh1
        ldA(p, 1, 1);
        VMW4();
        BAR();
        SCHEDBAR();
        mm(1);
    }
    // peeled last step (s = 17, p = 1): drain instead of count
    ldB(1, 0); ldA(1, 0, 0);
    mm(0);
    ldA(1, 0, 1);
    VMW0();
    BAR();
    SCHEDBAR();
    mm(1);
    ldB(1, 1); ldA(1, 1, 0);
    mm(0);
    ldA(1, 1, 1);
    mm(1);

    // ---- epilogue: bias + f32 store ----
    float bv[4];
#pragma unroll
    for (int nt = 0; nt < 4; ++nt)
        bv[nt] = bias[cls * FOUT + wn * 64 + nt * 16 + l15];

    float* ob = out + ((size_t)b * 4096 + (size_t)pt * 256) * FOUT;
#pragma unroll
    for (int mt = 0; mt < 8; ++mt) {
#pragma unroll
        for (int r = 0; r < 4; ++r) {
            const int row = wm * 128 + mt * 16 + l4 * 4 + r;
            float* orow = ob + (size_t)row * FOUT;
#pragma unroll
            for (int nt = 0; nt < 4; ++nt)
                orow[wn * 64 + nt * 16 + l15] = acc[mt][nt][r] + bv[nt];
        }
    }
}

// ===========================================================================
// Fallback path (round-2 kernels) if ws_size < WS_NEED
// ===========================================================================
__global__ __launch_bounds__(256) void prep_w_fb(const float* __restrict__ kin,
                                                 __bf16* __restrict__ wt) {
    __shared__ __bf16 tile[128 * 260];
    const int slab = blockIdx.x;
    const float* src = kin + (size_t)slab * (CINX * FOUT);
    __bf16* dst = wt + (size_t)slab * (16 * 256 * 8);
    const int t = threadIdx.x;
#pragma unroll
    for (int i = 0; i < 32; ++i) {
        int e4 = t + i * 256;
        int c = e4 >> 6, f4 = e4 & 63;
        f32x4 v = *(const f32x4*)(src + (size_t)e4 * 4);
        __bf16* p = &tile[c * 260 + f4 * 4];
        p[0] = (__bf16)v[0]; p[1] = (__bf16)v[1];
        p[2] = (__bf16)v[2]; p[3] = (__bf16)v[3];
    }
    __syncthreads();
#pragma unroll
    for (int i = 0; i < 16; ++i) {
        int g = t + i * 256;
        int cu = g >> 8, f = g & 255;
        bf16x8 o;
#pragma unroll
        for (int j = 0; j < 8; ++j) o[j] = tile[(cu * 8 + j) * 260 + f];
        *(bf16x8*)(dst + (size_t)g * 8) = o;
    }
}

__global__ __launch_bounds__(512, 2) void conv_fb(
    const float* __restrict__ xg, const int* __restrict__ cls_g,
    const __bf16* __restrict__ wt, const float* __restrict__ bias,
    float* __restrict__ out) {
    __shared__ __align__(16) __bf16 ldsA[2][8 * 256 * 8];
    __shared__ __align__(16) __bf16 ldsB[2][8 * 256 * 8];
    const int bid0 = blockIdx.x;
    const int swz = (bid0 & 7) * 64 + (bid0 >> 3);
    const int b = swz >> 4, pt = swz & 15;
    const int cls = cls_g[b];
    const int y0 = pt << 2;
    const int tid = threadIdx.x, lane = tid & 63, wid = tid >> 6;
    const int wm = wid >> 2, wn = wid & 3, l15 = lane & 15, l4 = lane >> 4;
    const float* xb = xg + (size_t)b * 4096 * CINX;
    const __bf16* wcls = wt + (size_t)cls * 9 * (16 * 256 * 8);
    const int tpx = tid >> 1, tch = (tid & 1) * 32;
    const int py = tpx >> 6, px_ = tpx & 63;
    f32x4 acc[8][4];
#pragma unroll
    for (int i = 0; i < 8; ++i)
#pragma unroll
        for (int j = 0; j < 4; ++j)
#pragma unroll
            for (int r = 0; r < 4; ++r) acc[i][j][r] = 0.f;
    f32x4 va[8];
    auto issueB = [&](int s, int buf) {
        const int tap = s >> 1, chalf = (s & 1) << 6;
        const __bf16* wsrc = wcls + (size_t)tap * (16 * 256 * 8) + chalf * 256;
#pragma unroll
        for (int i = 0; i < 4; ++i) {
            const int u = i * 512 + tid;
            gl16(wsrc + (size_t)u * 8, &ldsB[buf][(size_t)u * 8]);
        }
    };
    auto issueA = [&](int s) {
        const int tap = s >> 1, chalf = (s & 1) << 6;
        const int dy = tap / 3 - 1, dx = tap % 3 - 1;
        const int gy = y0 + py + dy, gx = px_ + dx;
        const bool valid = ((unsigned)gy < 64u) && ((unsigned)gx < 64u);
        const float* src = xb + ((size_t)(gy * 64 + gx)) * CINX + chalf + tch;
        if (valid) {
#pragma unroll
            for (int j2 = 0; j2 < 8; ++j2) va[j2] = *(const f32x4*)(src + j2 * 4);
        } else {
#pragma unroll
            for (int j2 = 0; j2 < 8; ++j2)
#pragma unroll
                for (int q = 0; q < 4; ++q) va[j2][q] = 0.f;
        }
    };
    auto writeA = [&](int buf) {
#pragma unroll
        for (int j = 0; j < 4; ++j) {
            bf16x8 pk;
#pragma unroll
            for (int q = 0; q < 4; ++q) {
                pk[q] = (__bf16)va[2 * j][q];
                pk[4 + q] = (__bf16)va[2 * j + 1][q];
            }
            const int u = ((tid & 1) * 4 + j) * 256 + tpx;
            *(bf16x8*)(&ldsA[buf][(size_t)u * 8]) = pk;
        }
    };
    auto compute = [&](int buf) {
#pragma unroll
        for (int kk = 0; kk < 2; ++kk) {
            const int cu = kk * 4 + l4;
            bf16x8 afr[8], bfr[4];
#pragma unroll
            for (int mt = 0; mt < 8; ++mt)
                afr[mt] = *(const bf16x8*)(
                    &ldsA[buf][(size_t)(cu * 256 + wm * 128 + mt * 16 + l15) * 8]);
#pragma unroll
            for (int nt = 0; nt < 4; ++nt)
                bfr[nt] = *(const bf16x8*)(
                    &ldsB[buf][(size_t)(cu * 256 + wn * 64 + nt * 16 + l15) * 8]);
#pragma unroll
            for (int mt = 0; mt < 8; ++mt)
#pragma unroll
                for (int nt = 0; nt < 4; ++nt)
                    acc[mt][nt] = __builtin_amdgcn_mfma_f32_16x16x32_bf16(
                        afr[mt], bfr[nt], acc[mt][nt], 0, 0, 0);
        }
    };
    issueB(0, 0);
    issueA(0);
    writeA(0);
    __syncthreads();
    int cur = 0;
    for (int s = 0; s < NSTEP - 1; ++s) {
        issueB(s + 1, cur ^ 1);
        issueA(s + 1);
        compute(cur);
        writeA(cur ^ 1);
        __syncthreads();
        cur ^= 1;
    }
    compute(cur);
    float bv[4];
#pragma unroll
    for (int nt = 0; nt < 4; ++nt)
        bv[nt] = bias[cls * FOUT + wn * 64 + nt * 16 + l15];
    float* ob = out + ((size_t)b * 4096 + (size_t)pt * 256) * FOUT;
#pragma unroll
    for (int mt = 0; mt < 8; ++mt) {
#pragma unroll
        for (int r = 0; r < 4; ++r) {
            const int row = wm * 128 + mt * 16 + l4 * 4 + r;
            float* orow = ob + (size_t)row * FOUT;
#pragma unroll
            for (int nt = 0; nt < 4; ++nt)
                orow[wn * 64 + nt * 16 + l15] = acc[mt][nt][r] + bv[nt];
        }
    }
}

extern "C" void kernel_launch(void* const* d_in, const int* in_sizes, int n_in,
                              void* d_out, int out_size, void* d_ws, size_t ws_size,
                              hipStream_t stream) {
    const float* x       = (const float*)d_in[0];
    const int*   classes = (const int*)d_in[1];
    const float* kin     = (const float*)d_in[2];
    const float* bias    = (const float*)d_in[3];
    float* out = (float*)d_out;

    char* ws = (char*)d_ws;
    __bf16* wt   = (__bf16*)ws;
    __bf16* zbuf = (__bf16*)(ws + WT_BYTES);
    __bf16* x16  = (__bf16*)(ws + WT_BYTES + Z_BYTES);

    if (ws_size >= WS_NEED) {
        prep_all<<<dim3(NCLS * 9 + 8192), dim3(256), 0, stream>>>(kin, wt, x,
                                                                  x16, zbuf);
        conv_main8<<<dim3(512), dim3(512), 0, stream>>>(x16, classes, wt, bias,
                                                        zbuf, out);
    } else {
        prep_w_fb<<<dim3(NCLS * 9), dim3(256), 0, stream>>>(kin, wt);
        conv_fb<<<dim3(512), dim3(512), 0, stream>>>(x, classes, wt, bias, out);
    }
}

// Round 5
// 100.316 us; speedup vs baseline: 1.7502x; 1.0141x over previous
//
#include <hip/hip_runtime.h>
#include <stdint.h>

#define BATCH 32
#define CINX 128
#define FOUT 256
#define NCLS 10
#define NSTEP 18   // 9 taps x 2 c-halves of 64

typedef __bf16 bf16x8 __attribute__((ext_vector_type(8)));
typedef float f32x4 __attribute__((ext_vector_type(4)));

#define WT_SLAB 32768                                  // bf16 per (cls,tap)
#define WT_BYTES ((size_t)NCLS * 9 * WT_SLAB * 2)      // 5,898,240
#define Z_BYTES 4096
#define X16_BYTES ((size_t)BATCH * 4096 * CINX * 2)    // 33,554,432
#define WS_NEED (WT_BYTES + Z_BYTES + X16_BYTES)

#define BAR() __builtin_amdgcn_s_barrier()
#define SCHEDBAR() __builtin_amdgcn_sched_barrier(0)
#define VMW4() asm volatile("s_waitcnt vmcnt(4)" ::: "memory")
#define VMW0() asm volatile("s_waitcnt vmcnt(0)" ::: "memory")

__device__ __forceinline__ void gl16(const __bf16* g, __bf16* l) {
    __builtin_amdgcn_global_load_lds(
        (const __attribute__((address_space(1))) void*)g,
        (__attribute__((address_space(3))) void*)l, 16, 0, 0);
}

// ---------------------------------------------------------------------------
// prep_all: fused weight transpose+convert and x convert (one launch).
// blocks 0..89: kernel [cls][tap][c][f] f32 -> wt [slab][h=c/32][f][slot]
//   bf16, pre-swizzled (slot holds c-chunk cu = slot ^ ((f>>1)&3)).
// blocks 90.. : x f32 -> bf16 flat; block 90 also zeroes the pad slab.
// ---------------------------------------------------------------------------
__global__ __launch_bounds__(256) void prep_all(const float* __restrict__ kin,
                                                __bf16* __restrict__ wt,
                                                const float* __restrict__ x,
                                                __bf16* __restrict__ x16,
                                                __bf16* __restrict__ zbuf) {
    if (blockIdx.x < NCLS * 9) {
        __shared__ __bf16 tile[128 * 260];
        const int slab = blockIdx.x;
        const float* src = kin + (size_t)slab * (CINX * FOUT);
        __bf16* dst = wt + (size_t)slab * WT_SLAB;
        const int t = threadIdx.x;
#pragma unroll
        for (int i = 0; i < 32; ++i) {
            int e4 = t + i * 256;
            int c = e4 >> 6, f4 = e4 & 63;
            f32x4 v = *(const f32x4*)(src + (size_t)e4 * 4);
            __bf16* p = &tile[c * 260 + f4 * 4];
            p[0] = (__bf16)v[0]; p[1] = (__bf16)v[1];
            p[2] = (__bf16)v[2]; p[3] = (__bf16)v[3];
        }
        __syncthreads();
#pragma unroll
        for (int i = 0; i < 16; ++i) {
            int g = t + i * 256;          // 16B unit within slab
            int h = g >> 10;              // 32-c half
            int u = g & 1023;
            int f = u >> 2, slot = u & 3;
            int cu = slot ^ ((f >> 1) & 3);
            int c0 = h * 32 + cu * 8;
            bf16x8 o;
#pragma unroll
            for (int j = 0; j < 8; ++j) o[j] = tile[(c0 + j) * 260 + f];
            *(bf16x8*)(dst + (size_t)g * 8) = o;
        }
    } else {
        const int bx = blockIdx.x - NCLS * 9;
        const size_t u = (size_t)bx * 256 + threadIdx.x;  // 8-elem unit
        f32x4 a = *(const f32x4*)(x + u * 8);
        f32x4 c = *(const f32x4*)(x + u * 8 + 4);
        bf16x8 o;
#pragma unroll
        for (int j = 0; j < 4; ++j) { o[j] = (__bf16)a[j]; o[4 + j] = (__bf16)c[j]; }
        *(bf16x8*)(x16 + u * 8) = o;
        if (bx == 0 && threadIdx.x < 128) {
            bf16x8 z;
#pragma unroll
            for (int j = 0; j < 8; ++j) z[j] = (__bf16)0.f;
            *(bf16x8*)(zbuf + (size_t)threadIdx.x * 8) = z;
        }
    }
}

// ---------------------------------------------------------------------------
// conv_main8: 256px x 256f tile, BK=64 as 2x32-c halves, 18 K-steps, 8 waves
// (2Mx4N), per-wave 128x64 out. Quad-buffered LDS (parity x kk). Minimal
// barrier set (2 publish barriers/step). NEW: one-phase-ahead register
// prefetch of A/B fragments (AA[2][4], BB[2][4]) so every 16-MFMA cluster's
// operands were issued a full phase earlier -> ds_read latency off the
// critical path. setprio(1) around MFMA clusters.
// ---------------------------------------------------------------------------
__global__ __launch_bounds__(512, 2) void conv_main8(
    const __bf16* __restrict__ xg16, const int* __restrict__ cls_g,
    const __bf16* __restrict__ wt, const float* __restrict__ bias,
    const __bf16* __restrict__ zbuf, float* __restrict__ out) {
    __shared__ __align__(16) __bf16 ldsA[2][2][1024 * 8];  // 64 KB
    __shared__ __align__(16) __bf16 ldsB[2][2][1024 * 8];  // 64 KB

    const int bid0 = blockIdx.x;
    const int swz  = (bid0 & 7) * 64 + (bid0 >> 3);   // XCD swizzle, bijective
    const int b    = swz >> 4;
    const int pt   = swz & 15;
    const int cls  = cls_g[b];
    const int y0   = pt << 2;

    const int tid  = threadIdx.x;
    const int lane = tid & 63;
    const int wid  = tid >> 6;
    const int wm   = wid >> 2;   // 0..1
    const int wn   = wid & 3;    // 0..3
    const int l15  = lane & 15;
    const int l4   = lane >> 4;

    const __bf16* xb   = xg16 + (size_t)b * 4096 * CINX;
    const __bf16* wcls = wt + (size_t)cls * 9 * WT_SLAB;

    // ---- loop-invariant staging coords (i=0,1 -> unit u = i*512+tid) ----
    int pyA[2], gxA[2], cuoffA[2], uS[2];
#pragma unroll
    for (int i = 0; i < 2; ++i) {
        int u = i * 512 + tid;
        int px = u >> 2, slot = u & 3;
        uS[i] = u;
        pyA[i] = px >> 6;
        gxA[i] = px & 63;
        cuoffA[i] = (slot ^ ((px >> 1) & 3)) * 8;
    }
    // ---- loop-invariant fragment-read units ----
    int unA[8], unB[4];
#pragma unroll
    for (int mt = 0; mt < 8; ++mt) {
        int px = wm * 128 + mt * 16 + l15;
        unA[mt] = px * 4 + (l4 ^ ((px >> 1) & 3));
    }
#pragma unroll
    for (int nt = 0; nt < 4; ++nt) {
        int f = wn * 64 + nt * 16 + l15;
        unB[nt] = f * 4 + (l4 ^ ((f >> 1) & 3));
    }

    f32x4 acc[8][4];
#pragma unroll
    for (int i = 0; i < 8; ++i)
#pragma unroll
        for (int j = 0; j < 4; ++j)
#pragma unroll
            for (int r = 0; r < 4; ++r) acc[i][j][r] = 0.f;

    // stage one 32-c half of step s2 (4 gload_lds/thread: 2 A + 2 B)
    auto stage = [&](int s2, int kk) {
        const int p = s2 & 1;
        const int tap = s2 >> 1;
        const int dy = tap / 3 - 1, dx = tap % 3 - 1;
        const int choff = (s2 & 1) * 64 + kk * 32;
#pragma unroll
        for (int i = 0; i < 2; ++i) {
            const int gy = y0 + pyA[i] + dy;
            const int gx = gxA[i] + dx;
            const bool v = ((unsigned)gy < 64u) && ((unsigned)gx < 64u);
            const __bf16* src = v
                ? (xb + ((size_t)(gy * 64 + gx)) * CINX + choff + cuoffA[i])
                : (zbuf + (size_t)(uS[i] & 63) * 8);
            gl16(src, &ldsA[p][kk][(size_t)uS[i] * 8]);
        }
        const __bf16* wsrc = wcls + (size_t)tap * WT_SLAB +
                             (size_t)((s2 & 1) * 2 + kk) * 8192;
#pragma unroll
        for (int i = 0; i < 2; ++i)
            gl16(wsrc + (size_t)uS[i] * 8, &ldsB[p][kk][(size_t)uS[i] * 8]);
    };

    // double-buffered fragment registers (one-phase-ahead prefetch)
    bf16x8 AA[2][4], BB[2][4];
    auto rdA = [&](int set, int p, int kk, int mh) {
#pragma unroll
        for (int mt = 0; mt < 4; ++mt)
            AA[set][mt] =
                *(const bf16x8*)&ldsA[p][kk][(size_t)unA[mh * 4 + mt] * 8];
    };
    auto rdB = [&](int set, int p, int kk) {
#pragma unroll
        for (int nt = 0; nt < 4; ++nt)
            BB[set][nt] = *(const bf16x8*)&ldsB[p][kk][(size_t)unB[nt] * 8];
    };
    auto mm = [&](int aset, int bset, int mh) {
        __builtin_amdgcn_s_setprio(1);
#pragma unroll
        for (int mt = 0; mt < 4; ++mt)
#pragma unroll
            for (int nt = 0; nt < 4; ++nt)
                acc[mh * 4 + mt][nt] = __builtin_amdgcn_mfma_f32_16x16x32_bf16(
                    AA[aset][mt], BB[bset][nt], acc[mh * 4 + mt][nt], 0, 0, 0);
        __builtin_amdgcn_s_setprio(0);
    };

    // prologue: both halves of step 0 in flight; land k0 (publish), k1 flying;
    // prefetch first fragment set.
    stage(0, 0);
    stage(0, 1);
    VMW4();
    BAR();
    SCHEDBAR();
    rdB(0, 0, 0);
    rdA(0, 0, 0, 0);

    for (int s = 0; s < NSTEP - 1; ++s) {
        const int p = s & 1;
        // ph0: prefetch A(k0,mh1)->set1; issue next-step k0; mm(k0,mh0) on set0
        rdA(1, p, 0, 1);
        stage(s + 1, 0);
        mm(0, 0, 0);
        // ph1: land [s,k1]; publish; prefetch B(k1)+A(k1,mh0)->set0; mm(k0,mh1)
        VMW4();
        BAR();
        SCHEDBAR();
        rdB(1, p, 1);
        rdA(0, p, 1, 0);
        mm(1, 0, 1);
        // ph2: prefetch A(k1,mh1)->set1; issue next-step k1; mm(k1,mh0) on set0
        rdA(1, p, 1, 1);
        stage(s + 1, 1);
        mm(0, 1, 0);
        // ph3: land [s+1,k0]; publish; prefetch B+A of (s+1,k0,mh0)->set0;
        //      mm(k1,mh1) on set1
        VMW4();
        BAR();
        SCHEDBAR();
        rdB(0, p ^ 1, 0);
        rdA(0, p ^ 1, 0, 0);
        mm(1, 1, 1);
    }
    // peeled last step (s = 17, p = 1): drain instead of count
    rdA(1, 1, 0, 1);
    mm(0, 0, 0);
    VMW0();
    BAR();
    SCHEDBAR();
    rdB(1, 1, 1);
    rdA(0, 1, 1, 0);
    mm(1, 0, 1);
    rdA(1, 1, 1, 1);
    mm(0, 1, 0);
    mm(1, 1, 1);

    // ---- epilogue: bias + f32 store ----
    float bv[4];
#pragma unroll
    for (int nt = 0; nt < 4; ++nt)
        bv[nt] = bias[cls * FOUT + wn * 64 + nt * 16 + l15];

    float* ob = out + ((size_t)b * 4096 + (size_t)pt * 256) * FOUT;
#pragma unroll
    for (int mt = 0; mt < 8; ++mt) {
#pragma unroll
        for (int r = 0; r < 4; ++r) {
            const int row = wm * 128 + mt * 16 + l4 * 4 + r;
            float* orow = ob + (size_t)row * FOUT;
#pragma unroll
            for (int nt = 0; nt < 4; ++nt)
                orow[wn * 64 + nt * 16 + l15] = acc[mt][nt][r] + bv[nt];
        }
    }
}

// ===========================================================================
// Fallback path (round-2 kernels) if ws_size < WS_NEED
// ===========================================================================
__global__ __launch_bounds__(256) void prep_w_fb(const float* __restrict__ kin,
                                                 __bf16* __restrict__ wt) {
    __shared__ __bf16 tile[128 * 260];
    const int slab = blockIdx.x;
    const float* src = kin + (size_t)slab * (CINX * FOUT);
    __bf16* dst = wt + (size_t)slab * (16 * 256 * 8);
    const int t = threadIdx.x;
#pragma unroll
    for (int i = 0; i < 32; ++i) {
        int e4 = t + i * 256;
        int c = e4 >> 6, f4 = e4 & 63;
        f32x4 v = *(const f32x4*)(src + (size_t)e4 * 4);
        __bf16* p = &tile[c * 260 + f4 * 4];
        p[0] = (__bf16)v[0]; p[1] = (__bf16)v[1];
        p[2] = (__bf16)v[2]; p[3] = (__bf16)v[3];
    }
    __syncthreads();
#pragma unroll
    for (int i = 0; i < 16; ++i) {
        int g = t + i * 256;
        int cu = g >> 8, f = g & 255;
        bf16x8 o;
#pragma unroll
        for (int j = 0; j < 8; ++j) o[j] = tile[(cu * 8 + j) * 260 + f];
        *(bf16x8*)(dst + (size_t)g * 8) = o;
    }
}

__global__ __launch_bounds__(512, 2) void conv_fb(
    const float* __restrict__ xg, const int* __restrict__ cls_g,
    const __bf16* __restrict__ wt, const float* __restrict__ bias,
    float* __restrict__ out) {
    __shared__ __align__(16) __bf16 ldsA[2][8 * 256 * 8];
    __shared__ __align__(16) __bf16 ldsB[2][8 * 256 * 8];
    const int bid0 = blockIdx.x;
    const int swz = (bid0 & 7) * 64 + (bid0 >> 3);
    const int b = swz >> 4, pt = swz & 15;
    const int cls = cls_g[b];
    const int y0 = pt << 2;
    const int tid = threadIdx.x, lane = tid & 63, wid = tid >> 6;
    const int wm = wid >> 2, wn = wid & 3, l15 = lane & 15, l4 = lane >> 4;
    const float* xb = xg + (size_t)b * 4096 * CINX;
    const __bf16* wcls = wt + (size_t)cls * 9 * (16 * 256 * 8);
    const int tpx = tid >> 1, tch = (tid & 1) * 32;
    const int py = tpx >> 6, px_ = tpx & 63;
    f32x4 acc[8][4];
#pragma unroll
    for (int i = 0; i < 8; ++i)
#pragma unroll
        for (int j = 0; j < 4; ++j)
#pragma unroll
            for (int r = 0; r < 4; ++r) acc[i][j][r] = 0.f;
    f32x4 va[8];
    auto issueB = [&](int s, int buf) {
        const int tap = s >> 1, chalf = (s & 1) << 6;
        const __bf16* wsrc = wcls + (size_t)tap * (16 * 256 * 8) + chalf * 256;
#pragma unroll
        for (int i = 0; i < 4; ++i) {
            const int u = i * 512 + tid;
            gl16(wsrc + (size_t)u * 8, &ldsB[buf][(size_t)u * 8]);
        }
    };
    auto issueA = [&](int s) {
        const int tap = s >> 1, chalf = (s & 1) << 6;
        const int dy = tap / 3 - 1, dx = tap % 3 - 1;
        const int gy = y0 + py + dy, gx = px_ + dx;
        const bool valid = ((unsigned)gy < 64u) && ((unsigned)gx < 64u);
        const float* src = xb + ((size_t)(gy * 64 + gx)) * CINX + chalf + tch;
        if (valid) {
#pragma unroll
            for (int j2 = 0; j2 < 8; ++j2) va[j2] = *(const f32x4*)(src + j2 * 4);
        } else {
#pragma unroll
            for (int j2 = 0; j2 < 8; ++j2)
#pragma unroll
                for (int q = 0; q < 4; ++q) va[j2][q] = 0.f;
        }
    };
    auto writeA = [&](int buf) {
#pragma unroll
        for (int j = 0; j < 4; ++j) {
            bf16x8 pk;
#pragma unroll
            for (int q = 0; q < 4; ++q) {
                pk[q] = (__bf16)va[2 * j][q];
                pk[4 + q] = (__bf16)va[2 * j + 1][q];
            }
            const int u = ((tid & 1) * 4 + j) * 256 + tpx;
            *(bf16x8*)(&ldsA[buf][(size_t)u * 8]) = pk;
        }
    };
    auto compute = [&](int buf) {
#pragma unroll
        for (int kk = 0; kk < 2; ++kk) {
            const int cu = kk * 4 + l4;
            bf16x8 afr[8], bfr[4];
#pragma unroll
            for (int mt = 0; mt < 8; ++mt)
                afr[mt] = *(const bf16x8*)(
                    &ldsA[buf][(size_t)(cu * 256 + wm * 128 + mt * 16 + l15) * 8]);
#pragma unroll
            for (int nt = 0; nt < 4; ++nt)
                bfr[nt] = *(const bf16x8*)(
                    &ldsB[buf][(size_t)(cu * 256 + wn * 64 + nt * 16 + l15) * 8]);
#pragma unroll
            for (int mt = 0; mt < 8; ++mt)
#pragma unroll
                for (int nt = 0; nt < 4; ++nt)
                    acc[mt][nt] = __builtin_amdgcn_mfma_f32_16x16x32_bf16(
                        afr[mt], bfr[nt], acc[mt][nt], 0, 0, 0);
        }
    };
    issueB(0, 0);
    issueA(0);
    writeA(0);
    __syncthreads();
    int cur = 0;
    for (int s = 0; s < NSTEP - 1; ++s) {
        issueB(s + 1, cur ^ 1);
        issueA(s + 1);
        compute(cur);
        writeA(cur ^ 1);
        __syncthreads();
        cur ^= 1;
    }
    compute(cur);
    float bv[4];
#pragma unroll
    for (int nt = 0; nt < 4; ++nt)
        bv[nt] = bias[cls * FOUT + wn * 64 + nt * 16 + l15];
    float* ob = out + ((size_t)b * 4096 + (size_t)pt * 256) * FOUT;
#pragma unroll
    for (int mt = 0; mt < 8; ++mt) {
#pragma unroll
        for (int r = 0; r < 4; ++r) {
            const int row = wm * 128 + mt * 16 + l4 * 4 + r;
            float* orow = ob + (size_t)row * FOUT;
#pragma unroll
            for (int nt = 0; nt < 4; ++nt)
                orow[wn * 64 + nt * 16 + l15] = acc[mt][nt][r] + bv[nt];
        }
    }
}

extern "C" void kernel_launch(void* const* d_in, const int* in_sizes, int n_in,
                              void* d_out, int out_size, void* d_ws, size_t ws_size,
                              hipStream_t stream) {
    const float* x       = (const float*)d_in[0];
    const int*   classes = (const int*)d_in[1];
    const float* kin     = (const float*)d_in[2];
    const float* bias    = (const float*)d_in[3];
    float* out = (float*)d_out;

    char* ws = (char*)d_ws;
    __bf16* wt   = (__bf16*)ws;
    __bf16* zbuf = (__bf16*)(ws + WT_BYTES);
    __bf16* x16  = (__bf16*)(ws + WT_BYTES + Z_BYTES);

    if (ws_size >= WS_NEED) {
        prep_all<<<dim3(NCLS * 9 + 8192), dim3(256), 0, stream>>>(kin, wt, x,
                                                                  x16, zbuf);
        conv_main8<<<dim3(512), dim3(512), 0, stream>>>(x16, classes, wt, bias,
                                                        zbuf, out);
    } else {
        prep_w_fb<<<dim3(NCLS * 9), dim3(256), 0, stream>>>(kin, wt);
        conv_fb<<<dim3(512), dim3(512), 0, stream>>>(x, classes, wt, bias, out);
    }
}